// Round 1
// 295.701 us; speedup vs baseline: 1.0330x; 1.0330x over previous
//
#include <hip/hip_runtime.h>
#include <hip/hip_bf16.h>
#include <hip/hip_fp16.h>

// DownEdgeMP, round 5: packed-f16 atomic scatter (global_atomic_pk_add_f16).
// Theory: angle_mlp is bound by device-scope atomic service rate (~178G ops/s,
// WRITE_SIZE == full atomic payload -> write-through). Halve ops+bytes by
// pairing adjacent cols via __shfl_xor and issuing 2xf16 packed atomics.
// angle MLP 264(->320)->128->128 over A edges; scatter to f16 sums/f32 cnt;
// edge MLP [aggr|e2] 256->128->128 over E2 nodes.
// Per block: 4 waves x (16 rows x 128 cols). Weights: bf16 W^T[128][KP],
// 16B-block XOR(n&7) swizzle, streamed through 2x16KB LDS chunks.

using u16    = unsigned short;
using u16x8  = __attribute__((ext_vector_type(8))) unsigned short;
using bf16x8 = __attribute__((ext_vector_type(8))) short;
using f32x4  = __attribute__((ext_vector_type(4))) float;

constexpr int H   = 128;
constexpr int NTH = 256;

__device__ __forceinline__ u16 f2bf(float f) {          // prep only
    union { float f; unsigned u; } x; x.f = f;
    unsigned r = x.u + 0x7FFFu + ((x.u >> 16) & 1u);
    return (u16)(r >> 16);
}
__device__ __forceinline__ unsigned cvt2(float x, float y) {
    union { __hip_bfloat162 h; unsigned u; } c;
    c.h = __float22bfloat162_rn(make_float2(x, y));     // v_cvt_pk_bf16_f32
    return c.u;
}
__device__ __forceinline__ bf16x8 cvt8(float4 a, float4 b) {
    union { unsigned u[4]; bf16x8 v; } o;
    o.u[0] = cvt2(a.x, a.y); o.u[1] = cvt2(a.z, a.w);
    o.u[2] = cvt2(b.x, b.y); o.u[3] = cvt2(b.z, b.w);
    return o.v;
}
__device__ __forceinline__ float4 ld4(const float* p) { return *(const float4*)p; }
__device__ __forceinline__ float h2f(u16 u) {
    union { u16 u; __half h; } c; c.u = u;
    return __half2float(c.h);
}
__device__ __forceinline__ float selu_f(float x) {
    const float scale = 1.0507009873554804934193349852946f;
    const float sa    = 1.0507009873554805f * 1.6732632423543772848170429916717f;
    return x > 0.0f ? scale * x : sa * (__expf(x) - 1.0f);
}

// ---- weight chunk staging: 128 rows x 64 k (16 KB) ----
__device__ __forceinline__ void load_wchunk(const u16* __restrict__ wt, int KPu, int c,
                                            int tid, u16x8 st[4]) {
#pragma unroll
    for (int s = 0; s < 4; ++s) {
        int i = s * NTH + tid;                 // 0..1023
        int n = i >> 3, jj = i & 7;
        st[s] = *(const u16x8*)(wt + (size_t)n * KPu + (c * 8 + jj) * 8);
    }
}
__device__ __forceinline__ void write_wchunk(u16* wb, int tid, const u16x8 st[4]) {
#pragma unroll
    for (int s = 0; s < 4; ++s) {
        int i = s * NTH + tid;
        *(u16x8*)(wb + i * 8) = st[s];
    }
}

template<int NKS>
__device__ __forceinline__ void mfma_chunk(const u16* cur, const bf16x8* afc,
                                           int ml, int kq, f32x4 acc[8]) {
#pragma unroll
    for (int ks = 0; ks < NKS; ++ks) {
        bf16x8 a = afc[ks];
#pragma unroll
        for (int sc = 0; sc < 8; ++sc) {
            bf16x8 b = *(const bf16x8*)&cur[(sc * 16 + ml) * 64 +
                                            (((ks * 4 + kq) ^ (ml & 7)) << 3)];
            acc[sc] = __builtin_amdgcn_mfma_f32_16x16x32_bf16(a, b, acc[sc], 0, 0, 0);
        }
    }
}

// W0-style: stream NCHUNK 64-K chunks through double-buffered LDS.
template<int NCHUNK, int LAST_NKS>
__device__ __forceinline__ void stream_layer(const u16* __restrict__ wt, int KPu,
                                             const bf16x8* af, u16* wb0, u16* wb1,
                                             int tid, int ml, int kq, f32x4 acc[8]) {
    u16x8 st[4];
    load_wchunk(wt, KPu, 0, tid, st);
    write_wchunk(wb0, tid, st);
    __syncthreads();
#pragma unroll
    for (int c = 0; c < NCHUNK; ++c) {
        u16* cur = (c & 1) ? wb1 : wb0;
        u16* nxt = (c & 1) ? wb0 : wb1;
        if (c + 1 < NCHUNK) load_wchunk(wt, KPu, c + 1, tid, st);   // issue early
        if (c == NCHUNK - 1) mfma_chunk<LAST_NKS>(cur, af + 2 * c, ml, kq, acc);
        else                 mfma_chunk<2>(cur, af + 2 * c, ml, kq, acc);
        if (c + 1 < NCHUNK) write_wchunk(nxt, tid, st);             // write late
        __syncthreads();
    }
}

// K=128 layer: preload both 64-K chunks, single barrier.
__device__ __forceinline__ void preload2_layer(const u16* __restrict__ wt,
                                               const bf16x8* af, u16* wb0, u16* wb1,
                                               int tid, int ml, int kq, f32x4 acc[8]) {
    u16x8 s0[4], s1[4];
    load_wchunk(wt, 128, 0, tid, s0);
    load_wchunk(wt, 128, 1, tid, s1);
    write_wchunk(wb0, tid, s0);
    write_wchunk(wb1, tid, s1);
    __syncthreads();
    mfma_chunk<2>(wb0, af + 0, ml, kq, acc);
    mfma_chunk<2>(wb1, af + 2, ml, kq, acc);
}

__device__ __forceinline__ void init_acc(const float* __restrict__ b, int ml, f32x4 acc[8]) {
#pragma unroll
    for (int sc = 0; sc < 8; ++sc) {
        float bv = b[sc * 16 + ml];
        acc[sc] = f32x4{bv, bv, bv, bv};
    }
}

// SELU(acc) -> bf16 -> hbuf[64][136] (padded stride: b128 reads hit 8-cyc floor)
__device__ __forceinline__ void store_h_selu(const f32x4 acc[8], u16* hbuf,
                                             int w, int ml, int kq) {
#pragma unroll
    for (int sc = 0; sc < 8; ++sc)
#pragma unroll
        for (int r = 0; r < 4; r += 2) {
            unsigned u = cvt2(selu_f(acc[sc][r]), selu_f(acc[sc][r + 1]));
            int rowb = w * 16 + kq * 4 + r;
            hbuf[rowb * 136 + sc * 16 + ml]       = (u16)u;
            hbuf[(rowb + 1) * 136 + sc * 16 + ml] = (u16)(u >> 16);
        }
}
__device__ __forceinline__ void read_af_h(const u16* hbuf, int w, int ml, int kq,
                                          bf16x8 af[4]) {
#pragma unroll
    for (int f = 0; f < 4; ++f)            // col = f*32 + kq*8
        af[f] = *(const bf16x8*)&hbuf[(w * 16 + ml) * 136 + f * 32 + kq * 8];
}

// ---- prep: fp32 W[K][128] -> bf16 W^T[128][KP], 16B-block XOR(n&7) swizzle ----
__global__ void prep_weights(const float* __restrict__ aW0, const float* __restrict__ aW1,
                             const float* __restrict__ aW2, const float* __restrict__ eW0,
                             const float* __restrict__ eW1, const float* __restrict__ eW2,
                             u16* __restrict__ dst)
{
    int t = blockIdx.x * 256 + threadIdx.x;
    const int nbs[6]  = {40, 16, 16, 32, 16, 16};
    const int Ks[6]   = {264, 128, 128, 256, 128, 128};
    const int offs[6] = {0, 40960, 57344, 73728, 106496, 122880};
    const float* Ws[6] = {aW0, aW1, aW2, eW0, eW1, eW2};
    int m = 0, rem = t;
    for (m = 0; m < 6; ++m) { int c = 128 * nbs[m]; if (rem < c) break; rem -= c; }
    if (m >= 6) return;
    const int nb = nbs[m];
    const int n = rem / nb, j = rem % nb;
    const int c = j >> 3, jj = j & 7;
    const int kb = jj ^ (n & 7);
    const int k0 = c * 64 + kb * 8;
    const int K = Ks[m];
    const float* W = Ws[m];
    union { u16 u[8]; u16x8 v; } o;
#pragma unroll
    for (int i = 0; i < 8; ++i) {
        int k = k0 + i;
        o.u[i] = (k < K) ? f2bf(W[k * H + n]) : (u16)0;
    }
    *(u16x8*)&dst[offs[m] + n * (nb * 8) + j * 8] = o.v;
}

// ---- angle MLP + packed-f16 atomic scatter ----
__global__ __launch_bounds__(NTH, 3) void angle_mlp(
    const float* __restrict__ e1, const float* __restrict__ e2,
    const float* __restrict__ a12, const int* __restrict__ idx,
    const u16* __restrict__ wt0, const u16* __restrict__ wt1, const u16* __restrict__ wt2,
    const float* __restrict__ b0, const float* __restrict__ b1, const float* __restrict__ b2,
    u16* __restrict__ sums, float* __restrict__ cnt, int A)
{
    __shared__ u16 wbuf[2][128 * 64];   // 32 KB
    __shared__ u16 hbuf[64 * 136];      // 17 KB

    const int tid = threadIdx.x;
    const int lane = tid & 63;
    const int ml = lane & 15, kq = lane >> 4;
    const int w = tid >> 6;
    const int ebase = blockIdx.x * 64;           // A % 64 == 0
    const int e = ebase + w * 16 + ml;
    const int rw = idx[e];
    const int cl = idx[A + e];
    if (kq == 0) atomicAdd(&cnt[cl], 1.0f);

    // gather x -> A-fragments in registers. frag f: k0 = f*32 + kq*8
    // k0==0 -> a12 | 8..128 -> e1[k0-8] | 136..256 -> e2[k0-136] | >=264 -> 0
    bf16x8 af[9];
    {
        const float* p1 = e1 + (size_t)rw * H;
        const float* p2 = e2 + (size_t)cl * H;
#pragma unroll
        for (int f = 0; f < 8; ++f) {
            int k0 = f * 32 + kq * 8;
            const float* p = (k0 == 0) ? (a12 + (size_t)e * 8)
                           : (k0 <= 128 ? p1 + (k0 - 8) : p2 + (k0 - 136));
            af[f] = cvt8(ld4(p), ld4(p + 4));
        }
        if (kq == 0) af[8] = cvt8(ld4(p2 + 120), ld4(p2 + 124));   // k0=256
        else { bf16x8 z = {0,0,0,0,0,0,0,0}; af[8] = z; }          // k0>=264
    }

    f32x4 acc[8];
    init_acc(b0, ml, acc);
    stream_layer<5, 1>(wt0, 320, af, wbuf[0], wbuf[1], tid, ml, kq, acc);

    store_h_selu(acc, hbuf, w, ml, kq);
    __syncthreads();
    bf16x8 af1[4];
    read_af_h(hbuf, w, ml, kq, af1);
    init_acc(b1, ml, acc);
    preload2_layer(wt1, af1, wbuf[0], wbuf[1], tid, ml, kq, acc);

    __syncthreads();                    // h1 reads + W1 B-reads done
    store_h_selu(acc, hbuf, w, ml, kq);
    __syncthreads();
    bf16x8 af2[4];
    read_af_h(hbuf, w, ml, kq, af2);
    init_acc(b2, ml, acc);
    preload2_layer(wt2, af2, wbuf[0], wbuf[1], tid, ml, kq, acc);

    // scatter-add via packed-f16 atomics (acc already includes bias).
    // C-layout: col = sc*16 + ml, row = kq*4 + r; adjacent cols live in lane
    // pair (ml, ml^1). One __shfl_xor swap per (sc,r) gives each lane the
    // partner column; even-ml lanes emit rows 0..1, odd-ml rows 2..3
    // -> 16 pk ops/thread instead of 32 f32 ops.
    const int rb = (ml & 1) * 2;
    const int i0 = A + ebase + w * 16 + kq * 4;
    const int clr0 = idx[i0 + rb];
    const int clr1 = idx[i0 + rb + 1];
#pragma unroll
    for (int sc = 0; sc < 8; ++sc) {
        float p0 = __shfl_xor(acc[sc][0], 1);
        float p1 = __shfl_xor(acc[sc][1], 1);
        float p2 = __shfl_xor(acc[sc][2], 1);
        float p3 = __shfl_xor(acc[sc][3], 1);
        float o0 = acc[sc][rb], o1 = acc[sc][rb + 1];
        float q0 = (ml & 1) ? p2 : p0;          // partner col value, my rows
        float q1 = (ml & 1) ? p3 : p1;
        float l0 = (ml & 1) ? q0 : o0, h0 = (ml & 1) ? o0 : q0;
        float l1 = (ml & 1) ? q1 : o1, h1 = (ml & 1) ? o1 : q1;
        union { __half2 h; unsigned u; } c0, c1;
        c0.h = __floats2half2_rn(l0, h0);
        c1.h = __floats2half2_rn(l1, h1);
        u16* d0 = sums + (size_t)clr0 * H + sc * 16 + (ml & ~1);
        u16* d1 = sums + (size_t)clr1 * H + sc * 16 + (ml & ~1);
        asm volatile("global_atomic_pk_add_f16 %0, %1, off" :: "v"(d0), "v"(c0.u) : "memory");
        asm volatile("global_atomic_pk_add_f16 %0, %1, off" :: "v"(d1), "v"(c1.u) : "memory");
    }
}

// ---- edge MLP ----
__global__ __launch_bounds__(NTH, 3) void edge_mlp(
    const float* __restrict__ e2, const u16* __restrict__ sums,
    const float* __restrict__ cnt,
    const u16* __restrict__ wt0, const u16* __restrict__ wt1, const u16* __restrict__ wt2,
    const float* __restrict__ b0, const float* __restrict__ b1, const float* __restrict__ b2,
    float* __restrict__ out, int E2n)
{
    __shared__ u16 wbuf[2][128 * 64];
    __shared__ u16 hbuf[64 * 136];

    const int tid = threadIdx.x;
    const int lane = tid & 63;
    const int ml = lane & 15, kq = lane >> 4;
    const int w = tid >> 6;
    const int nbase = blockIdx.x * 64;
    const int node = nbase + w * 16 + ml;
    const int nc = node < E2n ? node : E2n - 1;

    const float rcp = 1.0f / fmaxf(cnt[nc], 1.0f);
    // frag f: k0 = f*32 + kq*8; k0<128 -> f16 sums*rcp | else e2[k0-128]
    bf16x8 af[8];
    {
        const u16* ps = sums + (size_t)nc * H;
        const float* p2 = e2 + (size_t)nc * H;
#pragma unroll
        for (int f = 0; f < 8; ++f) {
            int k0 = f * 32 + kq * 8;
            float4 lo, hi;
            if (k0 < 128) {
                u16x8 hv = *(const u16x8*)(ps + k0);
                lo.x = h2f(hv[0]) * rcp; lo.y = h2f(hv[1]) * rcp;
                lo.z = h2f(hv[2]) * rcp; lo.w = h2f(hv[3]) * rcp;
                hi.x = h2f(hv[4]) * rcp; hi.y = h2f(hv[5]) * rcp;
                hi.z = h2f(hv[6]) * rcp; hi.w = h2f(hv[7]) * rcp;
            } else {
                lo = ld4(p2 + (k0 - 128));
                hi = ld4(p2 + (k0 - 124));
            }
            af[f] = cvt8(lo, hi);
        }
    }

    f32x4 acc[8];
    init_acc(b0, ml, acc);
    stream_layer<4, 2>(wt0, 256, af, wbuf[0], wbuf[1], tid, ml, kq, acc);

    store_h_selu(acc, hbuf, w, ml, kq);
    __syncthreads();
    bf16x8 af1[4];
    read_af_h(hbuf, w, ml, kq, af1);
    init_acc(b1, ml, acc);
    preload2_layer(wt1, af1, wbuf[0], wbuf[1], tid, ml, kq, acc);

    __syncthreads();
    store_h_selu(acc, hbuf, w, ml, kq);
    __syncthreads();
    bf16x8 af2[4];
    read_af_h(hbuf, w, ml, kq, af2);
    init_acc(b2, ml, acc);
    preload2_layer(wt2, af2, wbuf[0], wbuf[1], tid, ml, kq, acc);

#pragma unroll
    for (int r = 0; r < 4; ++r) {
        int nrow = nbase + w * 16 + kq * 4 + r;
        if (nrow < E2n) {
            float* dst = out + (size_t)nrow * H + ml;
#pragma unroll
            for (int sc = 0; sc < 8; ++sc)
                dst[sc * 16] = acc[sc][r];
        }
    }
}

extern "C" void kernel_launch(void* const* d_in, const int* in_sizes, int n_in,
                              void* d_out, int out_size, void* d_ws, size_t ws_size,
                              hipStream_t stream)
{
    const float* e1  = (const float*)d_in[0];
    const float* e2  = (const float*)d_in[1];
    const float* a12 = (const float*)d_in[2];
    const int*   idx = (const int*)d_in[3];
    const float* aW0 = (const float*)d_in[4];
    const float* ab0 = (const float*)d_in[5];
    const float* aW1 = (const float*)d_in[6];
    const float* ab1 = (const float*)d_in[7];
    const float* aW2 = (const float*)d_in[8];
    const float* ab2 = (const float*)d_in[9];
    const float* eW0 = (const float*)d_in[10];
    const float* eb0 = (const float*)d_in[11];
    const float* eW1 = (const float*)d_in[12];
    const float* eb1 = (const float*)d_in[13];
    const float* eW2 = (const float*)d_in[14];
    const float* eb2 = (const float*)d_in[15];

    const int E2n = in_sizes[1] / H;   // 100000
    const int A   = in_sizes[2] / 8;   // 400000

    char* ws = (char*)d_ws;
    u16*   wdst   = (u16*)ws;                                // 278528 B
    u16*   sums_h = (u16*)(ws + 278528);                     // f16 [E2][128]
    float* cnt    = (float*)(ws + 278528 + (size_t)E2n * H * 2);

    hipMemsetAsync(sums_h, 0, (size_t)E2n * H * 2 + (size_t)E2n * 4, stream);
    prep_weights<<<dim3(68), dim3(256), 0, stream>>>(aW0, aW1, aW2, eW0, eW1, eW2, wdst);

    angle_mlp<<<dim3(A / 64), dim3(NTH), 0, stream>>>(
        e1, e2, a12, idx, wdst + 0, wdst + 40960, wdst + 57344,
        ab0, ab1, ab2, sums_h, cnt, A);

    edge_mlp<<<dim3((E2n + 63) / 64), dim3(NTH), 0, stream>>>(
        e2, sums_h, cnt, wdst + 73728, wdst + 106496, wdst + 122880,
        eb0, eb1, eb2, (float*)d_out, E2n);
}